// Round 2
// baseline (118.670 us; speedup 1.0000x reference)
//
#include <hip/hip_runtime.h>
#include <math.h>

#define Bn 128
#define Dn 1024
#define Cn 1000
#define GAMMA 10.0f
#define EPSv 1e-6f

// ---------------- Kernel 1: correct logit per batch row + init max ----------------
__global__ __launch_bounds__(256) void k_correct(
    const float* __restrict__ A, const float* __restrict__ W,
    const float* __restrict__ bias, const int* __restrict__ tgt,
    float* __restrict__ ws_correct, unsigned int* __restrict__ ws_max)
{
    int b = blockIdx.x;
    int t = tgt[b];
    int tid = threadIdx.x;
    float acc = 0.f;
    for (int d = tid; d < Dn; d += 256) {
        acc += A[b * Dn + d] * W[d * Cn + t];
    }
    for (int off = 32; off; off >>= 1) acc += __shfl_down(acc, off, 64);
    __shared__ float s[4];
    if ((tid & 63) == 0) s[tid >> 6] = acc;
    __syncthreads();
    if (tid == 0) {
        ws_correct[b] = s[0] + s[1] + s[2] + s[3] + bias[t];
        ws_max[b] = 0u;   // harness poisons ws with 0xAA; must init
    }
}

// ---------------- Kernel 2: logits + dual-norm + violation max ----------------
__global__ __launch_bounds__(256) void k_violation(
    const float* __restrict__ A, const float* __restrict__ W,
    const float* __restrict__ bias, const int* __restrict__ tgt,
    const float* __restrict__ ws_correct, unsigned int* __restrict__ ws_max)
{
    const int b = blockIdx.y;
    const int tid = threadIdx.x;
    const int c = blockIdx.x * 256 + tid;
    const int t = tgt[b];

    __shared__ float As[Dn];
    __shared__ float Wt[Dn];
    for (int d = tid; d < Dn; d += 256) {
        As[d] = A[b * Dn + d];
        Wt[d] = W[d * Cn + t];   // strided but cached; only 1024 loads/block
    }
    __syncthreads();

    float logit = 0.f, dist = 0.f;
    if (c < Cn) {
        #pragma unroll 8
        for (int d = 0; d < Dn; ++d) {
            float w = W[d * Cn + c];     // coalesced across threads at each d
            logit = fmaf(As[d], w, logit);
            float df = w - Wt[d];
            dist = fmaf(df, df, dist);
        }
        logit += bias[c];
    }

    float viol = 0.f;
    if (c < Cn && c != t) {
        float dn = sqrtf(dist + EPSv) + EPSv;
        float sd = logit - ws_correct[b];
        viol = fmaxf(0.f, GAMMA + sd / dn);
    }

    // block max reduction (4 waves of 64)
    for (int off = 32; off; off >>= 1) viol = fmaxf(viol, __shfl_down(viol, off, 64));
    __shared__ float sm[4];
    if ((tid & 63) == 0) sm[tid >> 6] = viol;
    __syncthreads();
    if (tid == 0) {
        float m = fmaxf(fmaxf(sm[0], sm[1]), fmaxf(sm[2], sm[3]));
        // viol >= 0, so IEEE-as-uint ordering matches float ordering
        atomicMax(ws_max + b, __float_as_uint(m));
    }
}

// ---------------- Kernel 3: mean over batch ----------------
__global__ __launch_bounds__(128) void k_mean(
    const unsigned int* __restrict__ ws_max, float* __restrict__ out)
{
    int tid = threadIdx.x;   // 128 threads = 2 waves
    float v = __uint_as_float(ws_max[tid]);
    for (int off = 32; off; off >>= 1) v += __shfl_down(v, off, 64);
    __shared__ float s[2];
    if ((tid & 63) == 0) s[tid >> 6] = v;
    __syncthreads();
    if (tid == 0) out[0] = (s[0] + s[1]) * (1.0f / (float)Bn);
}

extern "C" void kernel_launch(void* const* d_in, const int* in_sizes, int n_in,
                              void* d_out, int out_size, void* d_ws, size_t ws_size,
                              hipStream_t stream) {
    const float* A    = (const float*)d_in[0];   // [B, D]
    const float* W    = (const float*)d_in[1];   // [D, C]
    const float* bias = (const float*)d_in[2];   // [C]
    const int*   tgt  = (const int*)d_in[3];     // [B]
    float* out = (float*)d_out;

    float*        ws_correct = (float*)d_ws;                  // [B]
    unsigned int* ws_max     = (unsigned int*)d_ws + Bn;      // [B]

    k_correct<<<dim3(Bn), dim3(256), 0, stream>>>(A, W, bias, tgt, ws_correct, ws_max);
    k_violation<<<dim3((Cn + 255) / 256, Bn), dim3(256), 0, stream>>>(
        A, W, bias, tgt, ws_correct, ws_max);
    k_mean<<<dim3(1), dim3(128), 0, stream>>>(ws_max, out);
}

// Round 3
// 99.177 us; speedup vs baseline: 1.1966x; 1.1966x over previous
//
#include <hip/hip_runtime.h>
#include <math.h>

#define Bn 128
#define Dn 1024
#define Cn 1000
#define Cpad 1024
#define GAMMA 10.0f
#define EPSv 1e-6f

#define DCH 8
#define DSPAN (Dn / DCH)   // 128
#define BM 4               // batch rows per block

// ws layout (floats):
//   ws_lg [Bn*Cpad]  : logits  Σ_d A[b,d] W[d,c]
//   ws_dot[Bn*Cpad]  : Σ_d W[d,t_b] W[d,c]
//   ws_nrm[Cpad]     : Σ_d W[d,c]^2
// all zero-initialized via hipMemsetAsync, accumulated with fp32 atomics.

// ---------------- Pass 1: split-K partial GEMM-ish accumulation ----------------
__global__ __launch_bounds__(256) void k_pass1(
    const float* __restrict__ A, const float* __restrict__ W,
    const int* __restrict__ tgt,
    float* __restrict__ ws_lg, float* __restrict__ ws_dot,
    float* __restrict__ ws_nrm)
{
    const int tid    = threadIdx.x;
    const int cchunk = blockIdx.x;   // 0..1  (512 columns each)
    const int bg     = blockIdx.y;   // 0..31 (4 batch rows each)
    const int dchunk = blockIdx.z;   // 0..7  (128 d each)
    const int b0 = bg * BM;
    const int d0 = dchunk * DSPAN;
    const int c  = cchunk * 512 + tid * 2;   // even; c valid => c+1 valid (Cn even)
    const bool valid = (c < Cn);
    const int cl = valid ? c : 0;            // clamped load column (stay in bounds)

    __shared__ float4 AsI[DSPAN];  // AsI[i].j = A[b0+j][d0+i]
    __shared__ float4 WtI[DSPAN];  // WtI[i].j = W[d0+i][tgt[b0+j]]

    for (int e = tid; e < DSPAN * BM; e += 256) {
        int i = e & (DSPAN - 1);
        int j = e >> 7;                      // DSPAN==128
        ((float*)&AsI[i])[j] = A[(b0 + j) * Dn + d0 + i];          // coalesced
        ((float*)&WtI[i])[j] = W[(d0 + i) * Cn + tgt[b0 + j]];     // strided, once
    }
    __syncthreads();

    float lgx[BM] = {0.f, 0.f, 0.f, 0.f}, lgy[BM] = {0.f, 0.f, 0.f, 0.f};
    float dtx[BM] = {0.f, 0.f, 0.f, 0.f}, dty[BM] = {0.f, 0.f, 0.f, 0.f};
    float sqx = 0.f, sqy = 0.f;

    const float* Wp = W + (size_t)d0 * Cn + cl;
    #pragma unroll 8
    for (int i = 0; i < DSPAN; ++i) {
        const float2 w = *(const float2*)(Wp + (size_t)i * Cn);
        const float4 a4 = AsI[i];
        const float4 t4 = WtI[i];
        const float ax[4] = {a4.x, a4.y, a4.z, a4.w};
        const float tx[4] = {t4.x, t4.y, t4.z, t4.w};
        #pragma unroll
        for (int j = 0; j < BM; ++j) {
            lgx[j] = fmaf(ax[j], w.x, lgx[j]);
            lgy[j] = fmaf(ax[j], w.y, lgy[j]);
            dtx[j] = fmaf(tx[j], w.x, dtx[j]);
            dty[j] = fmaf(tx[j], w.y, dty[j]);
        }
        sqx = fmaf(w.x, w.x, sqx);
        sqy = fmaf(w.y, w.y, sqy);
    }

    if (valid) {
        #pragma unroll
        for (int j = 0; j < BM; ++j) {
            atomicAdd(&ws_lg [(b0 + j) * Cpad + c    ], lgx[j]);
            atomicAdd(&ws_lg [(b0 + j) * Cpad + c + 1], lgy[j]);
            atomicAdd(&ws_dot[(b0 + j) * Cpad + c    ], dtx[j]);
            atomicAdd(&ws_dot[(b0 + j) * Cpad + c + 1], dty[j]);
        }
        if (bg == 0) {   // norms are b-independent: only one bgroup contributes
            atomicAdd(&ws_nrm[c    ], sqx);
            atomicAdd(&ws_nrm[c + 1], sqy);
        }
    }
}

// ---------------- Pass 2: violation, per-b max, mean via atomic ----------------
__global__ __launch_bounds__(256) void k_pass2(
    const float* __restrict__ ws_lg, const float* __restrict__ ws_dot,
    const float* __restrict__ ws_nrm, const float* __restrict__ bias,
    const int* __restrict__ tgt, float* __restrict__ out)
{
    const int b = blockIdx.x;
    const int tid = threadIdx.x;
    const int t = tgt[b];
    const float correct = ws_lg[b * Cpad + t] + bias[t];
    const float nt = ws_nrm[t];

    float m = 0.f;
    for (int c = tid; c < Cn; c += 256) {
        if (c == t) continue;
        float lg   = ws_lg [b * Cpad + c] + bias[c];
        float dist = ws_nrm[c] + nt - 2.f * ws_dot[b * Cpad + c];
        float dn   = sqrtf(dist + EPSv) + EPSv;
        float v    = GAMMA + (lg - correct) / dn;
        m = fmaxf(m, v);          // relu implicit: m starts at 0
    }
    for (int off = 32; off; off >>= 1) m = fmaxf(m, __shfl_down(m, off, 64));
    __shared__ float sm[4];
    if ((tid & 63) == 0) sm[tid >> 6] = m;
    __syncthreads();
    if (tid == 0) {
        float bm = fmaxf(fmaxf(sm[0], sm[1]), fmaxf(sm[2], sm[3]));
        atomicAdd(out, bm * (1.0f / (float)Bn));
    }
}

extern "C" void kernel_launch(void* const* d_in, const int* in_sizes, int n_in,
                              void* d_out, int out_size, void* d_ws, size_t ws_size,
                              hipStream_t stream) {
    const float* A    = (const float*)d_in[0];   // [B, D]
    const float* W    = (const float*)d_in[1];   // [D, C]
    const float* bias = (const float*)d_in[2];   // [C]
    const int*   tgt  = (const int*)d_in[3];     // [B]
    float* out = (float*)d_out;

    float* ws_lg  = (float*)d_ws;                 // [Bn*Cpad]
    float* ws_dot = ws_lg + Bn * Cpad;            // [Bn*Cpad]
    float* ws_nrm = ws_dot + Bn * Cpad;           // [Cpad]
    const size_t ws_floats = (size_t)2 * Bn * Cpad + Cpad;

    hipMemsetAsync(d_ws, 0, ws_floats * sizeof(float), stream);
    hipMemsetAsync(d_out, 0, sizeof(float), stream);

    k_pass1<<<dim3(2, Bn / BM / 1, DCH), dim3(256), 0, stream>>>(
        A, W, tgt, ws_lg, ws_dot, ws_nrm);
    // NOTE: grid.y must be Bn/BM = 32
    k_pass2<<<dim3(Bn), dim3(256), 0, stream>>>(ws_lg, ws_dot, ws_nrm, bias, tgt, out);
}

// Round 4
// 87.361 us; speedup vs baseline: 1.3584x; 1.1353x over previous
//
#include <hip/hip_runtime.h>
#include <math.h>

#define Bn 128
#define Dn 1024
#define Cn 1000
#define Cpad 1024
#define GAMMA 10.0f
#define EPSv 1e-6f

#define DCH 16
#define DSPAN (Dn / DCH)   // 64
#define BM 4
#define NBG (Bn / BM)      // 32

// ws layout (floats), all plain-stored by lm_partial (no init needed):
//   lg [DCH][Bn][Cpad]  partial logits   Σ_d A[b,d] W[d,c]
//   dt [DCH][Bn][Cpad]  partial dots     Σ_d W[d,t_b] W[d,c]
//   nrm[DCH][Cpad]      partial norms    Σ_d W[d,c]^2
// Total 16.1 MB of the 256 MB workspace.

// ---------------- Pass 1: split-K partials, no atomics ----------------
__global__ __launch_bounds__(256) void lm_partial(
    const float* __restrict__ A, const float* __restrict__ W,
    const int* __restrict__ tgt,
    float* __restrict__ lg, float* __restrict__ dt,
    float* __restrict__ nrm, float* __restrict__ out)
{
    const int tid = threadIdx.x;
    const int bg  = blockIdx.x;     // 0..31
    const int k   = blockIdx.y;     // 0..15
    if (bg == 0 && k == 0 && tid == 0) out[0] = 0.f;  // pass2 accumulates into out

    const int b0 = bg * BM;
    const int d0 = k * DSPAN;
    const int c0 = tid * 4;                 // 4 consecutive columns per thread
    const bool valid = (c0 < Cn);           // tid < 250
    const int c0m = valid ? c0 : 0;

    __shared__ float4 AsI[DSPAN];  // AsI[i].j = A[b0+j][d0+i]
    __shared__ float4 WtI[DSPAN];  // WtI[i].j = W[d0+i][tgt[b0+j]]
    {
        const int i = tid & (DSPAN - 1);
        const int j = tid >> 6;             // 256 threads = 64*4 exactly
        ((float*)&AsI[i])[j] = A[(b0 + j) * Dn + d0 + i];
        ((float*)&WtI[i])[j] = W[(size_t)(d0 + i) * Cn + tgt[b0 + j]];
    }
    __syncthreads();

    float aL[BM][4], aD[BM][4], aN[4];
    #pragma unroll
    for (int e = 0; e < 4; ++e) {
        aN[e] = 0.f;
        #pragma unroll
        for (int j = 0; j < BM; ++j) { aL[j][e] = 0.f; aD[j][e] = 0.f; }
    }

    const float* Wp = W + (size_t)d0 * Cn + c0m;   // (d*1000+c0)%4==0 -> 16B aligned
    #pragma unroll 4
    for (int i = 0; i < DSPAN; ++i) {
        const float4 w  = *(const float4*)(Wp + (size_t)i * Cn);
        const float4 a4 = AsI[i];               // LDS broadcast, conflict-free
        const float4 t4 = WtI[i];
        const float wv[4] = {w.x, w.y, w.z, w.w};
        const float av[4] = {a4.x, a4.y, a4.z, a4.w};
        const float tv[4] = {t4.x, t4.y, t4.z, t4.w};
        #pragma unroll
        for (int e = 0; e < 4; ++e) {
            aN[e] = fmaf(wv[e], wv[e], aN[e]);
            #pragma unroll
            for (int j = 0; j < BM; ++j) {
                aL[j][e] = fmaf(av[j], wv[e], aL[j][e]);
                aD[j][e] = fmaf(tv[j], wv[e], aD[j][e]);
            }
        }
    }

    if (valid) {
        #pragma unroll
        for (int j = 0; j < BM; ++j) {
            const size_t off = ((size_t)(k * Bn + b0 + j)) * Cpad + c0;
            *(float4*)&lg[off] = make_float4(aL[j][0], aL[j][1], aL[j][2], aL[j][3]);
            *(float4*)&dt[off] = make_float4(aD[j][0], aD[j][1], aD[j][2], aD[j][3]);
        }
        if (bg == 0)
            *(float4*)&nrm[(size_t)k * Cpad + c0] =
                make_float4(aN[0], aN[1], aN[2], aN[3]);
    }
}

// ---------------- Pass 2: reduce slices, violation, per-b max, mean ----------------
__global__ __launch_bounds__(256) void lm_final(
    const float* __restrict__ lg, const float* __restrict__ dt,
    const float* __restrict__ nrm, const float* __restrict__ bias,
    const int* __restrict__ tgt, float* __restrict__ out)
{
    const int b = blockIdx.x;
    const int tid = threadIdx.x;
    const int t = tgt[b];

    __shared__ float s_cr, s_nt;
    if (tid == 0) {
        float cr = 0.f, nt = 0.f;
        #pragma unroll
        for (int k = 0; k < DCH; ++k) {
            cr += lg[((size_t)(k * Bn + b)) * Cpad + t];
            nt += nrm[(size_t)k * Cpad + t];
        }
        s_cr = cr + bias[t];
        s_nt = nt;
    }
    __syncthreads();

    float m = 0.f;
    if (tid < 250) {
        const int c0 = tid * 4;
        float L[4] = {0.f,0.f,0.f,0.f}, Dt[4] = {0.f,0.f,0.f,0.f}, Nr[4] = {0.f,0.f,0.f,0.f};
        #pragma unroll
        for (int k = 0; k < DCH; ++k) {
            const float4 l4 = *(const float4*)&lg[((size_t)(k * Bn + b)) * Cpad + c0];
            const float4 d4 = *(const float4*)&dt[((size_t)(k * Bn + b)) * Cpad + c0];
            const float4 n4 = *(const float4*)&nrm[(size_t)k * Cpad + c0];
            L[0] += l4.x; L[1] += l4.y; L[2] += l4.z; L[3] += l4.w;
            Dt[0] += d4.x; Dt[1] += d4.y; Dt[2] += d4.z; Dt[3] += d4.w;
            Nr[0] += n4.x; Nr[1] += n4.y; Nr[2] += n4.z; Nr[3] += n4.w;
        }
        const float4 bi = *(const float4*)&bias[c0];
        const float bv[4] = {bi.x, bi.y, bi.z, bi.w};
        const float cr = s_cr, nt = s_nt;
        #pragma unroll
        for (int e = 0; e < 4; ++e) {
            const int c = c0 + e;
            if (c != t) {
                float dist = fmaxf(Nr[e] + nt - 2.f * Dt[e], 0.f);
                float dn   = sqrtf(dist + EPSv) + EPSv;
                float v    = GAMMA + (L[e] + bv[e] - cr) / dn;
                m = fmaxf(m, v);     // relu implicit: m starts at 0
            }
        }
    }

    for (int off = 32; off; off >>= 1) m = fmaxf(m, __shfl_down(m, off, 64));
    __shared__ float sm[4];
    if ((tid & 63) == 0) sm[tid >> 6] = m;
    __syncthreads();
    if (tid == 0) {
        const float bm = fmaxf(fmaxf(sm[0], sm[1]), fmaxf(sm[2], sm[3]));
        atomicAdd(out, bm * (1.0f / (float)Bn));
    }
}

extern "C" void kernel_launch(void* const* d_in, const int* in_sizes, int n_in,
                              void* d_out, int out_size, void* d_ws, size_t ws_size,
                              hipStream_t stream) {
    const float* A    = (const float*)d_in[0];   // [B, D]
    const float* W    = (const float*)d_in[1];   // [D, C]
    const float* bias = (const float*)d_in[2];   // [C]
    const int*   tgt  = (const int*)d_in[3];     // [B]
    float* out = (float*)d_out;

    float* lg  = (float*)d_ws;                       // [DCH][Bn][Cpad]
    float* dt  = lg + (size_t)DCH * Bn * Cpad;       // [DCH][Bn][Cpad]
    float* nrm = dt + (size_t)DCH * Bn * Cpad;       // [DCH][Cpad]

    lm_partial<<<dim3(NBG, DCH), dim3(256), 0, stream>>>(A, W, tgt, lg, dt, nrm, out);
    lm_final<<<dim3(Bn), dim3(256), 0, stream>>>(lg, dt, nrm, bias, tgt, out);
}

// Round 5
// 85.090 us; speedup vs baseline: 1.3946x; 1.0267x over previous
//
#include <hip/hip_runtime.h>
#include <math.h>

#define Bn 128
#define Dn 1024
#define Cn 1000
#define Cpad 1024
#define GAMMA 10.0f
#define EPSv 1e-6f

#define DCH 32
#define DSPAN (Dn / DCH)   // 32
#define BM 4
#define NBG (Bn / BM)      // 32

// ws layout (floats), all plain-stored by lm_partial (no init needed):
//   lg [DCH][Bn][Cpad]  partial logits   Σ_d A[b,d] W[d,c]
//   dt [DCH][Bn][Cpad]  partial dots     Σ_d W[d,t_b] W[d,c]
//   nrm[DCH][Cpad]      partial norms    Σ_d W[d,c]^2
// Total 33.6 MB of the 256 MB workspace.

// ---------------- Pass 1: split-K partials, no atomics ----------------
__global__ __launch_bounds__(256) void lm_partial(
    const float* __restrict__ A, const float* __restrict__ W,
    const int* __restrict__ tgt,
    float* __restrict__ lg, float* __restrict__ dt,
    float* __restrict__ nrm, float* __restrict__ out)
{
    const int tid = threadIdx.x;
    const int bg  = blockIdx.x;     // 0..31
    const int k   = blockIdx.y;     // 0..31
    if (bg == 0 && k == 0 && tid == 0) out[0] = 0.f;  // pass2 accumulates into out

    const int b0 = bg * BM;
    const int d0 = k * DSPAN;
    const int c0 = tid * 4;                 // 4 consecutive columns per thread
    const bool valid = (c0 < Cn);           // tid < 250
    const int c0m = valid ? c0 : 0;

    __shared__ float4 AsI[DSPAN];  // AsI[i].j = A[b0+j][d0+i]
    __shared__ float4 WtI[DSPAN];  // WtI[i].j = W[d0+i][tgt[b0+j]]
    if (tid < DSPAN * BM) {                 // 128 loader threads
        const int i = tid & (DSPAN - 1);
        const int j = tid >> 5;             // 0..3
        ((float*)&AsI[i])[j] = A[(b0 + j) * Dn + d0 + i];
        ((float*)&WtI[i])[j] = W[(size_t)(d0 + i) * Cn + tgt[b0 + j]];
    }
    __syncthreads();

    float aL[BM][4], aD[BM][4], aN[4];
    #pragma unroll
    for (int e = 0; e < 4; ++e) {
        aN[e] = 0.f;
        #pragma unroll
        for (int j = 0; j < BM; ++j) { aL[j][e] = 0.f; aD[j][e] = 0.f; }
    }

    const float* Wp = W + (size_t)d0 * Cn + c0m;   // (d*1000+c0)%4==0 -> 16B aligned
    #pragma unroll 4
    for (int i = 0; i < DSPAN; ++i) {
        const float4 w  = *(const float4*)(Wp + (size_t)i * Cn);
        const float4 a4 = AsI[i];               // uniform LDS broadcast
        const float4 t4 = WtI[i];
        const float wv[4] = {w.x, w.y, w.z, w.w};
        const float av[4] = {a4.x, a4.y, a4.z, a4.w};
        const float tv[4] = {t4.x, t4.y, t4.z, t4.w};
        #pragma unroll
        for (int e = 0; e < 4; ++e) {
            aN[e] = fmaf(wv[e], wv[e], aN[e]);
            #pragma unroll
            for (int j = 0; j < BM; ++j) {
                aL[j][e] = fmaf(av[j], wv[e], aL[j][e]);
                aD[j][e] = fmaf(tv[j], wv[e], aD[j][e]);
            }
        }
    }

    if (valid) {
        #pragma unroll
        for (int j = 0; j < BM; ++j) {
            const size_t off = ((size_t)(k * Bn + b0 + j)) * Cpad + c0;
            *(float4*)&lg[off] = make_float4(aL[j][0], aL[j][1], aL[j][2], aL[j][3]);
            *(float4*)&dt[off] = make_float4(aD[j][0], aD[j][1], aD[j][2], aD[j][3]);
        }
        if (bg == 0)
            *(float4*)&nrm[(size_t)k * Cpad + c0] =
                make_float4(aN[0], aN[1], aN[2], aN[3]);
    }
}

// ---------------- Pass 2: reduce slices, violation, per-b max, mean ----------------
__global__ __launch_bounds__(256) void lm_final(
    const float* __restrict__ lg, const float* __restrict__ dt,
    const float* __restrict__ nrm, const float* __restrict__ bias,
    const int* __restrict__ tgt, float* __restrict__ out)
{
    const int b = blockIdx.x;
    const int tid = threadIdx.x;
    const int t = tgt[b];

    __shared__ float s_cr, s_nt;
    if (tid < DCH) {   // 32 lanes of wave 0: parallel reduce of correct logit & target norm
        float cr = lg[((size_t)(tid * Bn + b)) * Cpad + t];
        float nt = nrm[(size_t)tid * Cpad + t];
        #pragma unroll
        for (int off = 16; off; off >>= 1) {
            cr += __shfl_down(cr, off, 64);
            nt += __shfl_down(nt, off, 64);
        }
        if (tid == 0) { s_cr = cr + bias[t]; s_nt = nt; }
    }
    __syncthreads();

    float m = 0.f;
    if (tid < 250) {
        const int c0 = tid * 4;
        float L[4] = {0.f,0.f,0.f,0.f}, Dt[4] = {0.f,0.f,0.f,0.f}, Nr[4] = {0.f,0.f,0.f,0.f};
        #pragma unroll 8
        for (int k = 0; k < DCH; ++k) {
            const float4 l4 = *(const float4*)&lg[((size_t)(k * Bn + b)) * Cpad + c0];
            const float4 d4 = *(const float4*)&dt[((size_t)(k * Bn + b)) * Cpad + c0];
            const float4 n4 = *(const float4*)&nrm[(size_t)k * Cpad + c0];
            L[0] += l4.x; L[1] += l4.y; L[2] += l4.z; L[3] += l4.w;
            Dt[0] += d4.x; Dt[1] += d4.y; Dt[2] += d4.z; Dt[3] += d4.w;
            Nr[0] += n4.x; Nr[1] += n4.y; Nr[2] += n4.z; Nr[3] += n4.w;
        }
        const float4 bi = *(const float4*)&bias[c0];
        const float bv[4] = {bi.x, bi.y, bi.z, bi.w};
        const float cr = s_cr, nt = s_nt;
        #pragma unroll
        for (int e = 0; e < 4; ++e) {
            const int c = c0 + e;
            if (c != t) {
                float dist = fmaxf(Nr[e] + nt - 2.f * Dt[e], 0.f);
                float dn   = sqrtf(dist + EPSv) + EPSv;
                float v    = GAMMA + (L[e] + bv[e] - cr) / dn;
                m = fmaxf(m, v);     // relu implicit: m starts at 0
            }
        }
    }

    for (int off = 32; off; off >>= 1) m = fmaxf(m, __shfl_down(m, off, 64));
    __shared__ float sm[4];
    if ((tid & 63) == 0) sm[tid >> 6] = m;
    __syncthreads();
    if (tid == 0) {
        const float bm = fmaxf(fmaxf(sm[0], sm[1]), fmaxf(sm[2], sm[3]));
        atomicAdd(out, bm * (1.0f / (float)Bn));
    }
}

extern "C" void kernel_launch(void* const* d_in, const int* in_sizes, int n_in,
                              void* d_out, int out_size, void* d_ws, size_t ws_size,
                              hipStream_t stream) {
    const float* A    = (const float*)d_in[0];   // [B, D]
    const float* W    = (const float*)d_in[1];   // [D, C]
    const float* bias = (const float*)d_in[2];   // [C]
    const int*   tgt  = (const int*)d_in[3];     // [B]
    float* out = (float*)d_out;

    float* lg  = (float*)d_ws;                       // [DCH][Bn][Cpad]
    float* dt  = lg + (size_t)DCH * Bn * Cpad;       // [DCH][Bn][Cpad]
    float* nrm = dt + (size_t)DCH * Bn * Cpad;       // [DCH][Cpad]

    lm_partial<<<dim3(NBG, DCH), dim3(256), 0, stream>>>(A, W, tgt, lg, dt, nrm, out);
    lm_final<<<dim3(Bn), dim3(256), 0, stream>>>(lg, dt, nrm, bias, tgt, out);
}

// Round 6
// 84.948 us; speedup vs baseline: 1.3970x; 1.0017x over previous
//
#include <hip/hip_runtime.h>
#include <math.h>

#define Bn 128
#define Dn 1024
#define Cn 1000
#define Cpad 1024
#define GAMMA 10.0f
#define EPSv 1e-6f

#define DCH 32
#define DSPAN (Dn / DCH)   // 32
#define BM 8               // batch rows per block (halves W L2 traffic vs BM=4)
#define NBG (Bn / BM)      // 16

// ws layout (floats), all plain-stored by lm_partial (no init needed):
//   lg [DCH][Bn][Cpad]  partial logits   Σ_d A[b,d] W[d,c]
//   dt [DCH][Bn][Cpad]  partial dots     Σ_d W[d,t_b] W[d,c]
//   nrm[DCH][Cpad]      partial norms    Σ_d W[d,c]^2
// Total 33.6 MB of the 256 MB workspace.

// ---------------- Pass 1: split-K partials, no atomics ----------------
__global__ __launch_bounds__(256) void lm_partial(
    const float* __restrict__ A, const float* __restrict__ W,
    const int* __restrict__ tgt,
    float* __restrict__ lg, float* __restrict__ dt,
    float* __restrict__ nrm, float* __restrict__ out)
{
    const int tid = threadIdx.x;
    const int bg  = blockIdx.x;     // 0..15
    const int k   = blockIdx.y;     // 0..31
    if (bg == 0 && k == 0 && tid == 0) out[0] = 0.f;  // pass2 accumulates into out

    const int b0 = bg * BM;
    const int d0 = k * DSPAN;
    const int c0 = tid * 4;                 // 4 consecutive columns per thread
    const bool valid = (c0 < Cn);           // tid < 250
    const int c0m = valid ? c0 : 0;

    // AsI[h][i].j = A[b0+4h+j][d0+i] ; WtI[h][i].j = W[d0+i][tgt[b0+4h+j]]
    __shared__ float4 AsI[2][DSPAN];
    __shared__ float4 WtI[2][DSPAN];
    {
        const int i = tid & (DSPAN - 1);    // 0..31
        const int j = tid >> 5;             // 0..7 (256 = 32*8 exactly)
        ((float*)&AsI[j >> 2][i])[j & 3] = A[(b0 + j) * Dn + d0 + i];
        ((float*)&WtI[j >> 2][i])[j & 3] = W[(size_t)(d0 + i) * Cn + tgt[b0 + j]];
    }
    __syncthreads();

    float aL[BM][4], aD[BM][4], aN[4];
    #pragma unroll
    for (int e = 0; e < 4; ++e) {
        aN[e] = 0.f;
        #pragma unroll
        for (int j = 0; j < BM; ++j) { aL[j][e] = 0.f; aD[j][e] = 0.f; }
    }

    const float* Wp = W + (size_t)d0 * Cn + c0m;   // (d*1000+c0)%4==0 -> 16B aligned
    #pragma unroll 2
    for (int i = 0; i < DSPAN; ++i) {
        const float4 w   = *(const float4*)(Wp + (size_t)i * Cn);
        const float4 a40 = AsI[0][i];           // uniform LDS broadcasts
        const float4 a41 = AsI[1][i];
        const float4 t40 = WtI[0][i];
        const float4 t41 = WtI[1][i];
        const float wv[4] = {w.x, w.y, w.z, w.w};
        const float av[8] = {a40.x, a40.y, a40.z, a40.w, a41.x, a41.y, a41.z, a41.w};
        const float tv[8] = {t40.x, t40.y, t40.z, t40.w, t41.x, t41.y, t41.z, t41.w};
        #pragma unroll
        for (int e = 0; e < 4; ++e) {
            aN[e] = fmaf(wv[e], wv[e], aN[e]);
            #pragma unroll
            for (int j = 0; j < BM; ++j) {
                aL[j][e] = fmaf(av[j], wv[e], aL[j][e]);
                aD[j][e] = fmaf(tv[j], wv[e], aD[j][e]);
            }
        }
    }

    if (valid) {
        #pragma unroll
        for (int j = 0; j < BM; ++j) {
            const size_t off = ((size_t)(k * Bn + b0 + j)) * Cpad + c0;
            *(float4*)&lg[off] = make_float4(aL[j][0], aL[j][1], aL[j][2], aL[j][3]);
            *(float4*)&dt[off] = make_float4(aD[j][0], aD[j][1], aD[j][2], aD[j][3]);
        }
        if (bg == 0)
            *(float4*)&nrm[(size_t)k * Cpad + c0] =
                make_float4(aN[0], aN[1], aN[2], aN[3]);
    }
}

// ---------------- Pass 2: reduce slices, violation, per-b max, mean ----------------
__global__ __launch_bounds__(256) void lm_final(
    const float* __restrict__ lg, const float* __restrict__ dt,
    const float* __restrict__ nrm, const float* __restrict__ bias,
    const int* __restrict__ tgt, float* __restrict__ out)
{
    const int b = blockIdx.x;
    const int tid = threadIdx.x;
    const int t = tgt[b];

    __shared__ float s_cr, s_nt;
    if (tid < DCH) {   // 32 lanes of wave 0: parallel reduce of correct logit & target norm
        float cr = lg[((size_t)(tid * Bn + b)) * Cpad + t];
        float nt = nrm[(size_t)tid * Cpad + t];
        #pragma unroll
        for (int off = 16; off; off >>= 1) {
            cr += __shfl_down(cr, off, 64);
            nt += __shfl_down(nt, off, 64);
        }
        if (tid == 0) { s_cr = cr + bias[t]; s_nt = nt; }
    }
    __syncthreads();

    float m = 0.f;
    if (tid < 250) {
        const int c0 = tid * 4;
        float L[4] = {0.f,0.f,0.f,0.f}, Dt[4] = {0.f,0.f,0.f,0.f}, Nr[4] = {0.f,0.f,0.f,0.f};
        #pragma unroll 8
        for (int k = 0; k < DCH; ++k) {
            const float4 l4 = *(const float4*)&lg[((size_t)(k * Bn + b)) * Cpad + c0];
            const float4 d4 = *(const float4*)&dt[((size_t)(k * Bn + b)) * Cpad + c0];
            const float4 n4 = *(const float4*)&nrm[(size_t)k * Cpad + c0];
            L[0] += l4.x; L[1] += l4.y; L[2] += l4.z; L[3] += l4.w;
            Dt[0] += d4.x; Dt[1] += d4.y; Dt[2] += d4.z; Dt[3] += d4.w;
            Nr[0] += n4.x; Nr[1] += n4.y; Nr[2] += n4.z; Nr[3] += n4.w;
        }
        const float4 bi = *(const float4*)&bias[c0];
        const float bv[4] = {bi.x, bi.y, bi.z, bi.w};
        const float cr = s_cr, nt = s_nt;
        #pragma unroll
        for (int e = 0; e < 4; ++e) {
            const int c = c0 + e;
            if (c != t) {
                float dist = fmaxf(Nr[e] + nt - 2.f * Dt[e], 0.f);
                float dn   = sqrtf(dist + EPSv) + EPSv;
                float v    = GAMMA + (L[e] + bv[e] - cr) / dn;
                m = fmaxf(m, v);     // relu implicit: m starts at 0
            }
        }
    }

    for (int off = 32; off; off >>= 1) m = fmaxf(m, __shfl_down(m, off, 64));
    __shared__ float sm[4];
    if ((tid & 63) == 0) sm[tid >> 6] = m;
    __syncthreads();
    if (tid == 0) {
        const float bm = fmaxf(fmaxf(sm[0], sm[1]), fmaxf(sm[2], sm[3]));
        atomicAdd(out, bm * (1.0f / (float)Bn));
    }
}

extern "C" void kernel_launch(void* const* d_in, const int* in_sizes, int n_in,
                              void* d_out, int out_size, void* d_ws, size_t ws_size,
                              hipStream_t stream) {
    const float* A    = (const float*)d_in[0];   // [B, D]
    const float* W    = (const float*)d_in[1];   // [D, C]
    const float* bias = (const float*)d_in[2];   // [C]
    const int*   tgt  = (const int*)d_in[3];     // [B]
    float* out = (float*)d_out;

    float* lg  = (float*)d_ws;                       // [DCH][Bn][Cpad]
    float* dt  = lg + (size_t)DCH * Bn * Cpad;       // [DCH][Bn][Cpad]
    float* nrm = dt + (size_t)DCH * Bn * Cpad;       // [DCH][Cpad]

    lm_partial<<<dim3(NBG, DCH), dim3(256), 0, stream>>>(A, W, tgt, lg, dt, nrm, out);
    lm_final<<<dim3(Bn), dim3(256), 0, stream>>>(lg, dt, nrm, bias, tgt, out);
}